// Round 6
// baseline (134.093 us; speedup 1.0000x reference)
//
#include <hip/hip_runtime.h>

// out = conv2d(poly(img), W, stride=1, pad=1) / 27, poly(v) = A0 + A1*v + A2*v^2
// (identity-kernel branch contributes exactly zero; 1/27 folded into poly).
// Implicit GEMM on bf16 MFMA: A = weights (M=o), B = poly(img) (N = spatial x),
// K = (ky,kx,c) = 576, mfma_f32_32x32x16_bf16.
//
// R10: half-chunk ping-pong DMA (R9 was 44 µs: pipe idle during every transform
// because single raw buffer forced dma(k+1) to wait for transform(k)).
//  - Two 8-ch raw slots (2 x 24576 B) + 16-ch stag (24960 B) = 74112 B dynamic,
//    SAME footprint as R9, 2 blocks/CU. dma(h+1) targets the slot transform(h)
//    is not reading -> issued right after the top __syncthreads(), so HBM has
//    loads in flight through transform, barrier waits, and (via a 2+1 split
//    around the stag barrier) through MFMA. Every vmcnt(0) drain now happens
//    with the pipe streaming, not empty.
//  - MFMA stays at 16-ch granularity: stag row (r*2 + ccl) with ccl = h&1
//    matches the MFMA half-lane selector exactly (cc8g = chunk*2 + half).
//  - Epilogue: direct full-line global stores from acc (unchanged from R9).

typedef __bf16 bf16;
typedef __attribute__((ext_vector_type(8))) __bf16 bf16x8;
typedef __attribute__((ext_vector_type(16))) float f32x16;

static constexpr float A0 = -0.000287f / 27.0f;
static constexpr float A1 =  0.266f    / 27.0f;
static constexpr float A2 = -0.1097f   / 27.0f;

#define NN 16
#define CI 64
#define HH 128
#define WW 128
#define OO 64
#define LDS_BYTES 74112   // 2*24576 raw slots + 24960 bf16 staging

// Repack weights [O][C][3][3] fp32 -> [slice=ky*3+kx][cc8=c/8][o][cj=c%8] bf16.
__global__ void repack_w(const float* __restrict__ w, bf16* __restrict__ wrb) {
    int idx = blockIdx.x * 256 + threadIdx.x;        // 9*8*64*8 = 36864
    if (idx >= 9 * 8 * 64 * 8) return;
    int cj    = idx & 7;
    int o     = (idx >> 3) & 63;
    int cc8   = (idx >> 9) & 7;
    int slice = idx >> 12;
    int ky = slice / 3, kx = slice - ky * 3;
    int c = cc8 * 8 + cj;
    wrb[idx] = (bf16)w[((o * CI + c) * 3 + ky) * 3 + kx];
}

__global__ __launch_bounds__(512, 4) void conv_mfma(const float* __restrict__ img,
                                                    const bf16* __restrict__ wrb,
                                                    float* __restrict__ out) {
    // slot[2]: [r 6][ch 8][x 128] f32 = 24576 B each (DMA targets, lane-linear)
    // ilds:    [r2 12][xp 130][cj 8] bf16 = 24960 B (MFMA B staging)
    extern __shared__ __align__(16) char smem[];
    float* slots = (float*)smem;                       // slot s at s*6144 floats
    bf16*  ilds  = (bf16*)(smem + 49152);

    const int tid = threadIdx.x;
    const int b   = blockIdx.x;
    const int y0  = (b & 31) * 4;
    const int n   = b >> 5;

    const int wv   = tid >> 6;
    const int lane = tid & 63;
    const int lm   = lane & 31;      // A: o-row / B: x-col / C: col
    const int half = lane >> 5;      // k-half selector (which cc8 of the pair)
    const int yl   = wv >> 1;
    const int Xh   = (wv & 1) * 64;

    // DMA instrs i in [i0,i1) of half-chunk h (8 channels) into slot[h&1].
    // 48 rows of 512 B = 24 1-KB pairs; instr q = wv + 8*i covers rows 2q,2q+1
    // (same input row r = q>>2, channels 2q&7, 2q&7+1). Lane l lands at
    // slot + q*1024 + 16*l  == [row 2q + (l>>5)][x 4*(l&31)] -- exactly linear.
    auto dma = [&](int h, int i0, int i1) {
        float* slot = slots + (h & 1) * 6144;
        const int cb = h * 8;
        for (int i = i0; i < i1; ++i) {
            const int q   = wv + 8 * i;
            const int r   = q >> 2;                 // input row 0..5
            const int ch0 = (2 * q) & 7;
            const int yi  = y0 - 1 + r;
            if ((unsigned)yi < 128u) {
                const float* g = img + ((n * CI + cb + ch0 + half) * HH + yi) * WW + lm * 4;
                __builtin_amdgcn_global_load_lds(
                    (const __attribute__((address_space(1))) void*)g,
                    (__attribute__((address_space(3))) void*)(slot + q * 256),
                    16, 0, 0);
            }
        }
    };

    // Transform half-chunk h: poly(slot[h&1]) -> stag rows (r*2 + (h&1)).
    // 390 items = 6r * 65xh, one item per thread (tid < 390).
    auto transform = [&](int h) {
        const float* slot = slots + (h & 1) * 6144;
        const int ccl = h & 1;
        if (tid < 390) {
            const int r  = tid / 65;
            const int xh = tid - r * 65;
            const int yi = y0 - 1 + r;
            bf16* rowp = ilds + (r * 2 + ccl) * (130 * 8);
            if (xh < 64) {
                bf16x8 pk0, pk1;
                if ((unsigned)yi < 128u) {
                    const float* p = slot + (r * 8) * 128 + 2 * xh;
                    #pragma unroll
                    for (int j = 0; j < 8; ++j) {
                        float2 v = *(const float2*)(p + j * 128);   // LDS b64, 2-way (free)
                        pk0[j] = (bf16)(A0 + v.x * (A1 + A2 * v.x));
                        pk1[j] = (bf16)(A0 + v.y * (A1 + A2 * v.y));
                    }
                } else {
                    #pragma unroll
                    for (int j = 0; j < 8; ++j) { pk0[j] = (bf16)0.0f; pk1[j] = (bf16)0.0f; }
                }
                *(bf16x8*)(rowp + (2 * xh + 1) * 8) = pk0;
                *(bf16x8*)(rowp + (2 * xh + 2) * 8) = pk1;
            } else {
                bf16x8 z;
                #pragma unroll
                for (int j = 0; j < 8; ++j) z[j] = (bf16)0.0f;
                *(bf16x8*)(rowp + 0) = z;            // xp=0   (xi=-1, conv pad)
                *(bf16x8*)(rowp + 129 * 8) = z;      // xp=129 (xi=128, conv pad)
            }
        }
    };

    f32x16 acc[2][2];
    #pragma unroll
    for (int i = 0; i < 2; ++i)
        #pragma unroll
        for (int j = 0; j < 2; ++j)
            #pragma unroll
            for (int k = 0; k < 16; ++k) acc[i][j][k] = 0.0f;

    const bf16x8* wfr = (const bf16x8*)wrb;
    const bf16x8* ifr = (const bf16x8*)ilds;

    dma(0, 0, 3);                                  // prologue: fill slot0

    for (int h = 0; h < 8; ++h) {
        __syncthreads();                           // drain: dma(h) complete+visible;
                                                   // also orders MFMA(prev) vs transform(h)
        if (h < 7) dma(h + 1, 0, 2);               // 2/3 of next: streams during transform
        transform(h);
        if (h & 1) {
            __syncthreads();                       // stag visible (lgkm); partA streamed
            if (h < 7) dma(h + 1, 2, 3);           // last 1/3: streams during MFMA
            const int cc8g = (h >> 1) * 2 + half;
            #pragma unroll
            for (int ky = 0; ky < 3; ++ky) {
                const int r = yl + ky;
                #pragma unroll
                for (int kx = 0; kx < 3; ++kx) {
                    const int slice = ky * 3 + kx;
                    bf16x8 a0 = wfr[(slice * 8 + cc8g) * 64 + lm];        // weights, L1-hot
                    bf16x8 a1 = wfr[(slice * 8 + cc8g) * 64 + 32 + lm];
                    const int ib = (r * 2 + half) * 130 + Xh + lm + kx;   // conflict-free b128
                    bf16x8 b0 = ifr[ib];
                    bf16x8 b1 = ifr[ib + 32];
                    acc[0][0] = __builtin_amdgcn_mfma_f32_32x32x16_bf16(a0, b0, acc[0][0], 0, 0, 0);
                    acc[0][1] = __builtin_amdgcn_mfma_f32_32x32x16_bf16(a0, b1, acc[0][1], 0, 0, 0);
                    acc[1][0] = __builtin_amdgcn_mfma_f32_32x32x16_bf16(a1, b0, acc[1][0], 0, 0, 0);
                    acc[1][1] = __builtin_amdgcn_mfma_f32_32x32x16_bf16(a1, b1, acc[1][1], 0, 0, 0);
                }
            }
        } else {
            if (h < 7) dma(h + 1, 2, 3);           // even h: issue rest immediately
        }
    }

    // ---- Epilogue: direct stores. Half-wave = 32 lanes x 4 B = one full
    // 128-B line per (o,y) segment; every output line written exactly once. ----
    // C/D layout: col = lane&31 (x), row-in-32 = (rg&3) + 8*(rg>>2) + 4*half (o).
    const int ybase = (n * OO * HH + (y0 + yl)) * WW;
    #pragma unroll
    for (int p = 0; p < 2; ++p)
        #pragma unroll
        for (int xt = 0; xt < 2; ++xt) {
            const int x = Xh + xt * 32 + lm;
            #pragma unroll
            for (int rg = 0; rg < 16; ++rg) {
                const int o = (rg & 3) + 8 * (rg >> 2) + 4 * half + 32 * p;
                out[ybase + o * (HH * WW) + x] = acc[p][xt][rg];
            }
        }
}

extern "C" void kernel_launch(void* const* d_in, const int* in_sizes, int n_in,
                              void* d_out, int out_size, void* d_ws, size_t ws_size,
                              hipStream_t stream) {
    const float* img = (const float*)d_in[0];
    const float* w   = (const float*)d_in[1];
    // d_in[2] (identity_kernel) unused: its branch convolves exact zeros.
    float* out = (float*)d_out;
    bf16* wrb  = (bf16*)d_ws;    // 36864 bf16 = 73728 B repacked weights

    static bool attr_done = false;
    if (!attr_done) {
        (void)hipFuncSetAttribute((const void*)conv_mfma,
                                  hipFuncAttributeMaxDynamicSharedMemorySize, LDS_BYTES);
        attr_done = true;
    }

    repack_w<<<(9 * 8 * 64 * 8 + 255) / 256, 256, 0, stream>>>(w, wrb);
    conv_mfma<<<NN * (HH / 4), 512, LDS_BYTES, stream>>>(img, wrb, out);
}